// Round 1
// baseline (155.597 us; speedup 1.0000x reference)
//
#include <hip/hip_runtime.h>
#include <stdint.h>

#define XC 4096      // CB*BS
#define MT 256       // batch rows per workgroup
#define NNZ 13       // nnz blocks per row block (setup guarantees)

typedef __attribute__((ext_vector_type(8))) short short8;
typedef __attribute__((ext_vector_type(4))) float f32x4;

static __device__ __forceinline__ unsigned short f2bf(float f) {
    union { float f; unsigned int u; } c; c.f = f;
    unsigned int u = c.u;
    unsigned int r = 0x7FFFu + ((u >> 16) & 1u);
    return (unsigned short)((u + r) >> 16);
}
static __device__ __forceinline__ unsigned int pk2(float a, float b) {
    return (unsigned int)f2bf(a) | ((unsigned int)f2bf(b) << 16);
}
// HW packed cvt (RTNE), 2 f32 -> 2 bf16 in one VALU op
static __device__ __forceinline__ unsigned int cvtpk(float lo, float hi) {
    unsigned int r;
    asm("v_cvt_pk_bf16_f32 %0, %1, %2" : "=v"(r) : "v"(lo), "v"(hi));
    return r;
}

// async global->LDS, 16B per lane; LDS dest = uniform base + lane*16
#define GLD_LDS16(g, l) __builtin_amdgcn_global_load_lds(                      \
    (const __attribute__((address_space(1))) void*)(g),                        \
    (__attribute__((address_space(3))) void*)(l), 16, 0, 0)

// ---- fused single-launch kernel: fp32 in, bf16 MFMA, no workspace ----
// grid = 128 r-blocks * 8 batch tiles; 4 waves; wave owns 64 batch rows.
// w*mask converted to bf16 frags in VGPRs in a prologue; x chunks fp32
// double-buffered in wave-private LDS via global_load_lds (source-side
// XOR swizzle, linear dest), converted to bf16 A-frags in registers.
// sync = s_waitcnt vmcnt(N) only; no barriers.
__global__ __launch_bounds__(256, 2) void bsl_fused(
    const float* __restrict__ x, const int* __restrict__ cols,
    const float* __restrict__ w, const float* __restrict__ m,
    const float* __restrict__ bias, float* __restrict__ out)
{
    // 4 waves * 2 bufs * (64 rows * 32 floats) = 64 KiB
    __shared__ __align__(16) float x_lds[4 * 2 * 2048];

    const int tid  = threadIdx.x;
    const int bx   = blockIdx.x;
    const int r    = bx & 127;    // consecutive blocks share batch tile -> L2
    const int mt   = bx >> 7;
    const int row0 = mt * MT;
    const int start = r * NNZ;

    const int lane = tid & 63;
    const int wv   = tid >> 6;
    const int l15  = lane & 15;
    const int quad = lane >> 4;

    int cseq[NNZ];
    #pragma unroll
    for (int nn = 0; nn < NNZ; ++nn) cseq[nn] = cols[start + nn];

    // B frags from fp32 w*mask: lane holds w[o = l15 (+16)][k = quad*8 + j]
    short8 wfrag[NNZ][2];
    {
        const float* wp = w + (size_t)start * 1024 + l15 * 32 + quad * 8;
        const float* mp = m + (size_t)start * 1024 + l15 * 32 + quad * 8;
        #pragma unroll
        for (int nn = 0; nn < NNZ; ++nn) {
            #pragma unroll
            for (int h = 0; h < 2; ++h) {
                const float* wq = wp + nn * 1024 + h * 512;
                const float* mq = mp + nn * 1024 + h * 512;
                f32x4 a0 = *(const f32x4*)wq;
                f32x4 a1 = *(const f32x4*)(wq + 4);
                f32x4 b0 = *(const f32x4*)mq;
                f32x4 b1 = *(const f32x4*)(mq + 4);
                union { short8 s; unsigned int u[4]; } fr;
                fr.u[0] = cvtpk(a0.x * b0.x, a0.y * b0.y);
                fr.u[1] = cvtpk(a0.z * b0.z, a0.w * b0.w);
                fr.u[2] = cvtpk(a1.x * b1.x, a1.y * b1.y);
                fr.u[3] = cvtpk(a1.z * b1.z, a1.w * b1.w);
                wfrag[nn][h] = fr.s;
            }
        }
    }

    // staging geometry (fp32): lane covers row rl = lane>>3 of each 8-row
    // group j, 16B unit usw = (lane&7) ^ rl  (XOR swizzle on SOURCE; LDS
    // dest linear = base + lane*16). Storage invariant:
    //   LDS[row][pos] holds global 16B-unit g with pos = g ^ (row&7).
    const int row0w = row0 + wv * 64;
    const int rl    = lane >> 3;
    const int usw   = (lane & 7) ^ rl;
    const float* xsrc = x + ((size_t)row0w + rl) * XC + usw * 4;
    float* lbase = &x_lds[wv * 4096];

    #pragma unroll
    for (int p = 0; p < 2; ++p) {   // issue chunks 0..1
        const float* g = xsrc + cseq[p] * 32;
        #pragma unroll
        for (int j = 0; j < 8; ++j)
            GLD_LDS16(g + (size_t)j * 8 * XC, lbase + p * 2048 + j * 256);
    }

    f32x4 acc[4][2];
    #pragma unroll
    for (int i = 0; i < 4; ++i)
        #pragma unroll
        for (int j = 0; j < 2; ++j)
            acc[i][j] = (f32x4){0.f, 0.f, 0.f, 0.f};

    // read-side swizzle: frag (rloc, quad) needs units g0=2q,g1=2q+1 at
    // positions u0 = 2q ^ (rloc&7), u0^1. rloc&7 == l15&7 (mi*16 ≡ 0 mod 8).
    const int u0 = (quad << 1) ^ (l15 & 7);

    #pragma unroll
    for (int nn = 0; nn < NNZ; ++nn) {
        // chunk nn complete when only the newest chunk remains outstanding
        if (nn < NNZ - 1) asm volatile("s_waitcnt vmcnt(8)" ::: "memory");
        else              asm volatile("s_waitcnt vmcnt(0)" ::: "memory");

        const float* xb = lbase + (nn & 1) * 2048;
        #pragma unroll
        for (int mi = 0; mi < 4; ++mi) {
            const int rloc = mi * 16 + l15;
            f32x4 v0 = *(const f32x4*)&xb[rloc * 32 + (u0       * 4)];
            f32x4 v1 = *(const f32x4*)&xb[rloc * 32 + ((u0 ^ 1) * 4)];
            union { short8 s; unsigned int u[4]; } fa;
            fa.u[0] = cvtpk(v0.x, v0.y);
            fa.u[1] = cvtpk(v0.z, v0.w);
            fa.u[2] = cvtpk(v1.x, v1.y);
            fa.u[3] = cvtpk(v1.z, v1.w);
            acc[mi][0] = __builtin_amdgcn_mfma_f32_16x16x32_bf16(fa.s, wfrag[nn][0], acc[mi][0], 0, 0, 0);
            acc[mi][1] = __builtin_amdgcn_mfma_f32_16x16x32_bf16(fa.s, wfrag[nn][1], acc[mi][1], 0, 0, 0);
        }
        // issue chunk nn+2 AFTER MFMAs: their lgkm waits guarantee this
        // buffer's ds_reads (in-order LDS) completed -> no WAR hazard
        if (nn + 2 < NNZ) {
            const int p = nn + 2;
            const float* g = xsrc + cseq[p] * 32;
            #pragma unroll
            for (int j = 0; j < 8; ++j)
                GLD_LDS16(g + (size_t)j * 8 * XC, lbase + (p & 1) * 2048 + j * 256);
        }
    }

    // epilogue: C/D layout col=l15(=o), row=quad*4+reg(=m)
    const float b0v = bias[r * 32 + l15];
    const float b1v = bias[r * 32 + 16 + l15];
    #pragma unroll
    for (int mi = 0; mi < 4; ++mi) {
        const int rbase = row0 + wv * 64 + mi * 16 + quad * 4;
        #pragma unroll
        for (int reg = 0; reg < 4; ++reg) {
            float* op = out + (size_t)(rbase + reg) * XC + r * 32;
            op[l15]      = acc[mi][0][reg] + b0v;
            op[16 + l15] = acc[mi][1][reg] + b1v;
        }
    }
}

// ---- fallback (unexpected shape): round-1 kernel, inline conv ----
__global__ __launch_bounds__(256, 3) void bsl_fallback(
    const float* __restrict__ x, const int* __restrict__ crow,
    const int* __restrict__ cols, const float* __restrict__ wf,
    const float* __restrict__ mf, const float* __restrict__ bias,
    float* __restrict__ out)
{
    __shared__ unsigned short w_lds[NNZ][32][40];
    __shared__ unsigned short x_lds[MT][40];

    const int tid = threadIdx.x;
    const int bx  = blockIdx.x;
    const int r   = bx & 127;
    const int mt  = bx >> 7;
    const int row0 = mt * MT;
    const int start = crow[r];
    const int nnzr  = crow[r + 1] - start;

    const float4* wsrc = (const float4*)(wf + (size_t)start * 1024);
    const float4* msrc = (const float4*)(mf + (size_t)start * 1024);
    for (int i = tid; i < nnzr * 256; i += 256) {
        int nn = i >> 8, rem = i & 255;
        int o = rem >> 3, sg = rem & 7;
        float4 a = wsrc[i], b = msrc[i];
        *(uint2*)&w_lds[nn][o][sg * 4] =
            make_uint2(pk2(a.x * b.x, a.y * b.y), pk2(a.z * b.z, a.w * b.w));
    }

    const int lane = tid & 63;
    const int wv   = tid >> 6;
    const int l15  = lane & 15;
    const int quad = lane >> 4;

    f32x4 acc[4][2];
    #pragma unroll
    for (int i = 0; i < 4; ++i)
        #pragma unroll
        for (int j = 0; j < 2; ++j)
            acc[i][j] = (f32x4){0.f, 0.f, 0.f, 0.f};

    const int s4 = tid & 7;
    const int rr = tid >> 3;
    float4 v[8];
    {
        int c = cols[start];
        const float* xb = x + (size_t)(row0 + rr) * XC + c * 32 + s4 * 4;
        #pragma unroll
        for (int j = 0; j < 8; ++j) v[j] = *(const float4*)(xb + (size_t)j * 32 * XC);
    }

    for (int nn = 0; nn < nnzr; ++nn) {
        __syncthreads();
        #pragma unroll
        for (int j = 0; j < 8; ++j)
            *(uint2*)&x_lds[rr + j * 32][s4 * 4] =
                make_uint2(pk2(v[j].x, v[j].y), pk2(v[j].z, v[j].w));
        __syncthreads();

        if (nn + 1 < nnzr) {
            int c = cols[start + nn + 1];
            const float* xb = x + (size_t)(row0 + rr) * XC + c * 32 + s4 * 4;
            #pragma unroll
            for (int j = 0; j < 8; ++j) v[j] = *(const float4*)(xb + (size_t)j * 32 * XC);
        }

        short8 b0 = *(const short8*)&w_lds[nn][l15][quad * 8];
        short8 b1 = *(const short8*)&w_lds[nn][16 + l15][quad * 8];
        #pragma unroll
        for (int mi = 0; mi < 4; ++mi) {
            short8 a = *(const short8*)&x_lds[wv * 64 + mi * 16 + l15][quad * 8];
            acc[mi][0] = __builtin_amdgcn_mfma_f32_16x16x32_bf16(a, b0, acc[mi][0], 0, 0, 0);
            acc[mi][1] = __builtin_amdgcn_mfma_f32_16x16x32_bf16(a, b1, acc[mi][1], 0, 0, 0);
        }
    }

    const float b0v = bias[r * 32 + l15];
    const float b1v = bias[r * 32 + 16 + l15];
    #pragma unroll
    for (int mi = 0; mi < 4; ++mi) {
        const int rbase = row0 + wv * 64 + mi * 16 + quad * 4;
        #pragma unroll
        for (int reg = 0; reg < 4; ++reg) {
            float* op = out + (size_t)(rbase + reg) * XC + r * 32;
            op[l15]      = acc[mi][0][reg] + b0v;
            op[16 + l15] = acc[mi][1][reg] + b1v;
        }
    }
}

extern "C" void kernel_launch(void* const* d_in, const int* in_sizes, int n_in,
                              void* d_out, int out_size, void* d_ws, size_t ws_size,
                              hipStream_t stream) {
    const float* x      = (const float*)d_in[0];
    const int*   crow   = (const int*)d_in[1];
    const int*   cols   = (const int*)d_in[2];
    const float* mask   = (const float*)d_in[3];
    const float* weight = (const float*)d_in[4];
    const float* bias   = (const float*)d_in[5];
    float* out = (float*)d_out;

    const int xel   = in_sizes[0];        // 2048*4096
    const int rb    = in_sizes[1] - 1;    // 128
    const int batch = xel / XC;           // 2048

    const bool fast = (rb == 128) && (in_sizes[2] == rb * NNZ) &&
                      (in_sizes[4] == rb * NNZ * 1024) && (batch % MT == 0);

    if (fast) {
        bsl_fused<<<dim3(rb * (batch / MT)), dim3(256), 0, stream>>>(
            x, cols, weight, mask, bias, out);
    } else {
        bsl_fallback<<<dim3(rb * (batch / MT)), dim3(256), 0, stream>>>(
            x, crow, cols, weight, mask, bias, out);
    }
}

// Round 3
// 121.516 us; speedup vs baseline: 1.2805x; 1.2805x over previous
//
#include <hip/hip_runtime.h>
#include <stdint.h>

#define XC 4096      // CB*BS
#define MT 256       // batch rows per workgroup (main path)
#define NNZ 13       // nnz blocks per row block (setup guarantees)

typedef __attribute__((ext_vector_type(8))) short short8;
typedef __attribute__((ext_vector_type(4))) float f32x4;

static __device__ __forceinline__ unsigned short f2bf(float f) {
    union { float f; unsigned int u; } c; c.f = f;
    unsigned int u = c.u;
    unsigned int r = 0x7FFFu + ((u >> 16) & 1u);
    return (unsigned short)((u + r) >> 16);
}
static __device__ __forceinline__ unsigned int pk2(float a, float b) {
    return (unsigned int)f2bf(a) | ((unsigned int)f2bf(b) << 16);
}

// async global->LDS, 16B per lane; LDS dest = uniform base + lane*16
#define GLD_LDS16(g, l) __builtin_amdgcn_global_load_lds(                      \
    (const __attribute__((address_space(1))) void*)(g),                        \
    (__attribute__((address_space(3))) void*)(l), 16, 0, 0)

// ---- prep: x fp32 -> bf16, w*mask fp32 -> bf16 (fused, one launch) ----
__global__ void prep(const float* __restrict__ x, const float* __restrict__ w,
                     const float* __restrict__ m, unsigned short* __restrict__ xbf,
                     unsigned short* __restrict__ wbf, int nx4, int nw4) {
    int i = blockIdx.x * 256 + threadIdx.x;
    if (i < nx4) {
        float4 a = ((const float4*)x)[i];
        ((uint2*)xbf)[i] = make_uint2(pk2(a.x, a.y), pk2(a.z, a.w));
    } else {
        int k = i - nx4;
        if (k < nw4) {
            float4 a = ((const float4*)w)[k];
            float4 b = ((const float4*)m)[k];
            ((uint2*)wbf)[k] = make_uint2(pk2(a.x * b.x, a.y * b.y),
                                          pk2(a.z * b.z, a.w * b.w));
        }
    }
}

// ---- main: barrier-free wave-private pipeline ----
// grid = 128 r-blocks * 8 batch tiles; 4 waves; wave owns 64 batch rows.
// w frags in VGPRs; x chunks triple-buffered in wave-private LDS via
// global_load_lds; sync = s_waitcnt vmcnt(N) only.
// XCD mapping: mt = bx & 7 so each XCD (bx % 8) owns ONE batch tile ->
// its unique xbf slice (2.1 MB) is L2-resident and the 13x per-chunk
// x reuse becomes L2 hits (was: all 8 tiles per XCD -> L3-served).
__global__ __launch_bounds__(256, 2) void bsl_mfma2(
    const unsigned short* __restrict__ xbf, const int* __restrict__ cols,
    const unsigned short* __restrict__ wbf, const float* __restrict__ bias,
    float* __restrict__ out)
{
    // 4 waves * 3 bufs * (64 rows * 32 shorts) = 48 KiB, XOR-swizzled
    __shared__ __align__(16) unsigned short x_lds[4 * 3 * 2048];

    const int tid  = threadIdx.x;
    const int bx   = blockIdx.x;
    const int mt   = bx & 7;      // XCD-pinned batch tile (grid = 128*8)
    const int r    = bx >> 3;
    const int row0 = mt * MT;
    const int start = r * NNZ;

    const int lane = tid & 63;
    const int wv   = tid >> 6;
    const int l15  = lane & 15;
    const int quad = lane >> 4;

    int cseq[NNZ];
    #pragma unroll
    for (int nn = 0; nn < NNZ; ++nn) cseq[nn] = cols[start + nn];

    // B frags: lane holds w[o = l15 (+16)][k = quad*8 + j]; coalesced 16B loads
    short8 wfrag[NNZ][2];
    {
        const unsigned short* wp0 = wbf + (size_t)start * 1024 + l15 * 32 + quad * 8;
        #pragma unroll
        for (int nn = 0; nn < NNZ; ++nn) {
            wfrag[nn][0] = *(const short8*)(wp0 + nn * 1024);
            wfrag[nn][1] = *(const short8*)(wp0 + nn * 1024 + 512);
        }
    }

    // staging geometry: lane covers row (j*16 + lane>>2), 16B unit
    // q = (lane&3) ^ ((lane>>3)&3)  (XOR swizzle; dest = base + lane*16)
    const int row0w = row0 + wv * 64;
    const int rl    = lane >> 2;
    const int qsw   = (lane & 3) ^ ((lane >> 3) & 3);
    const unsigned short* xsrc = xbf + ((size_t)row0w + rl) * XC + qsw * 8;
    unsigned short* lbase = &x_lds[wv * 6144];

    #pragma unroll
    for (int p = 0; p < 3; ++p) {   // issue chunks 0..2
        const unsigned short* g = xsrc + cseq[p] * 32;
        #pragma unroll
        for (int j = 0; j < 4; ++j)
            GLD_LDS16(g + (size_t)j * 16 * XC, lbase + p * 2048 + j * 512);
    }

    f32x4 acc[4][2];
    #pragma unroll
    for (int i = 0; i < 4; ++i)
        #pragma unroll
        for (int j = 0; j < 2; ++j)
            acc[i][j] = (f32x4){0.f, 0.f, 0.f, 0.f};

    const int sw = (l15 >> 1) & 3;   // read-side swizzle term

    #pragma unroll
    for (int nn = 0; nn < NNZ; ++nn) {
        // chunk nn complete when only the 2 newest chunks remain outstanding
        if (nn < NNZ - 2)       asm volatile("s_waitcnt vmcnt(8)" ::: "memory");
        else if (nn == NNZ - 2) asm volatile("s_waitcnt vmcnt(4)" ::: "memory");
        else                    asm volatile("s_waitcnt vmcnt(0)" ::: "memory");

        const unsigned short* xb = lbase + (nn % 3) * 2048;
        #pragma unroll
        for (int mi = 0; mi < 4; ++mi) {
            const int rloc = mi * 16 + l15;
            short8 a = *(const short8*)&xb[rloc * 32 + ((quad ^ sw) * 8)];
            acc[mi][0] = __builtin_amdgcn_mfma_f32_16x16x32_bf16(a, wfrag[nn][0], acc[mi][0], 0, 0, 0);
            acc[mi][1] = __builtin_amdgcn_mfma_f32_16x16x32_bf16(a, wfrag[nn][1], acc[mi][1], 0, 0, 0);
        }
        // issue chunk nn+3 AFTER MFMAs: their lgkm waits guarantee the
        // slot's ds_reads (in-order LDS) completed -> no WAR hazard
        if (nn + 3 < NNZ) {
            const int p = nn + 3;
            const unsigned short* g = xsrc + cseq[p] * 32;
            #pragma unroll
            for (int j = 0; j < 4; ++j)
                GLD_LDS16(g + (size_t)j * 16 * XC, lbase + (p % 3) * 2048 + j * 512);
        }
    }

    // epilogue: C/D layout col=l15(=o), row=quad*4+reg(=m)
    const float b0v = bias[r * 32 + l15];
    const float b1v = bias[r * 32 + 16 + l15];
    #pragma unroll
    for (int mi = 0; mi < 4; ++mi) {
        const int rbase = row0 + wv * 64 + mi * 16 + quad * 4;
        #pragma unroll
        for (int reg = 0; reg < 4; ++reg) {
            float* op = out + (size_t)(rbase + reg) * XC + r * 32;
            op[l15]      = acc[mi][0][reg] + b0v;
            op[16 + l15] = acc[mi][1][reg] + b1v;
        }
    }
}

// ---- fallback (ws too small / unexpected shape): inline-conversion kernel ----
__global__ __launch_bounds__(256, 3) void bsl_fallback(
    const float* __restrict__ x, const int* __restrict__ crow,
    const int* __restrict__ cols, const float* __restrict__ wf,
    const float* __restrict__ mf, const float* __restrict__ bias,
    float* __restrict__ out)
{
    __shared__ unsigned short w_lds[NNZ][32][40];
    __shared__ unsigned short x_lds[MT][40];

    const int tid = threadIdx.x;
    const int bx  = blockIdx.x;
    const int r   = bx & 127;
    const int mt  = bx >> 7;
    const int row0 = mt * MT;
    const int start = crow[r];
    const int nnzr  = crow[r + 1] - start;

    const float4* wsrc = (const float4*)(wf + (size_t)start * 1024);
    const float4* msrc = (const float4*)(mf + (size_t)start * 1024);
    for (int i = tid; i < nnzr * 256; i += 256) {
        int nn = i >> 8, rem = i & 255;
        int o = rem >> 3, sg = rem & 7;
        float4 a = wsrc[i], b = msrc[i];
        *(uint2*)&w_lds[nn][o][sg * 4] =
            make_uint2(pk2(a.x * b.x, a.y * b.y), pk2(a.z * b.z, a.w * b.w));
    }

    const int lane = tid & 63;
    const int wv   = tid >> 6;
    const int l15  = lane & 15;
    const int quad = lane >> 4;

    f32x4 acc[4][2];
    #pragma unroll
    for (int i = 0; i < 4; ++i)
        #pragma unroll
        for (int j = 0; j < 2; ++j)
            acc[i][j] = (f32x4){0.f, 0.f, 0.f, 0.f};

    const int s4 = tid & 7;
    const int rr = tid >> 3;
    float4 v[8];
    {
        int c = cols[start];
        const float* xb = x + (size_t)(row0 + rr) * XC + c * 32 + s4 * 4;
        #pragma unroll
        for (int j = 0; j < 8; ++j) v[j] = *(const float4*)(xb + (size_t)j * 32 * XC);
    }

    for (int nn = 0; nn < nnzr; ++nn) {
        __syncthreads();
        #pragma unroll
        for (int j = 0; j < 8; ++j)
            *(uint2*)&x_lds[rr + j * 32][s4 * 4] =
                make_uint2(pk2(v[j].x, v[j].y), pk2(v[j].z, v[j].w));
        __syncthreads();

        if (nn + 1 < nnzr) {
            int c = cols[start + nn + 1];
            const float* xb = x + (size_t)(row0 + rr) * XC + c * 32 + s4 * 4;
            #pragma unroll
            for (int j = 0; j < 8; ++j) v[j] = *(const float4*)(xb + (size_t)j * 32 * XC);
        }

        short8 b0 = *(const short8*)&w_lds[nn][l15][quad * 8];
        short8 b1 = *(const short8*)&w_lds[nn][16 + l15][quad * 8];
        #pragma unroll
        for (int mi = 0; mi < 4; ++mi) {
            short8 a = *(const short8*)&x_lds[wv * 64 + mi * 16 + l15][quad * 8];
            acc[mi][0] = __builtin_amdgcn_mfma_f32_16x16x32_bf16(a, b0, acc[mi][0], 0, 0, 0);
            acc[mi][1] = __builtin_amdgcn_mfma_f32_16x16x32_bf16(a, b1, acc[mi][1], 0, 0, 0);
        }
    }

    const float b0v = bias[r * 32 + l15];
    const float b1v = bias[r * 32 + 16 + l15];
    #pragma unroll
    for (int mi = 0; mi < 4; ++mi) {
        const int rbase = row0 + wv * 64 + mi * 16 + quad * 4;
        #pragma unroll
        for (int reg = 0; reg < 4; ++reg) {
            float* op = out + (size_t)(rbase + reg) * XC + r * 32;
            op[l15]      = acc[mi][0][reg] + b0v;
            op[16 + l15] = acc[mi][1][reg] + b1v;
        }
    }
}

extern "C" void kernel_launch(void* const* d_in, const int* in_sizes, int n_in,
                              void* d_out, int out_size, void* d_ws, size_t ws_size,
                              hipStream_t stream) {
    const float* x      = (const float*)d_in[0];
    const int*   crow   = (const int*)d_in[1];
    const int*   cols   = (const int*)d_in[2];
    const float* mask   = (const float*)d_in[3];
    const float* weight = (const float*)d_in[4];
    const float* bias   = (const float*)d_in[5];
    float* out = (float*)d_out;

    const int xel   = in_sizes[0];        // 2048*4096
    const int wel   = in_sizes[4];        // 1664*1024
    const int rb    = in_sizes[1] - 1;    // 128
    const int batch = xel / XC;           // 2048

    const size_t xb_bytes = (size_t)xel * 2;
    const size_t wb_bytes = (size_t)wel * 2;

    // fast path requires batch == 2048 (mt = bx & 7 mapping assumes 8 tiles)
    const bool fast = (ws_size >= xb_bytes + wb_bytes) && (rb == 128) &&
                      (in_sizes[2] == rb * NNZ) && (batch == MT * 8);

    if (fast) {
        unsigned short* xbf = (unsigned short*)d_ws;
        unsigned short* wbf = (unsigned short*)((char*)d_ws + xb_bytes);
        int nx4 = xel / 4, nw4 = wel / 4;
        int tot = nx4 + nw4;
        prep<<<dim3((tot + 255) / 256), dim3(256), 0, stream>>>(x, weight, mask,
                                                                xbf, wbf, nx4, nw4);
        bsl_mfma2<<<dim3(rb * (batch / MT)), dim3(256), 0, stream>>>(xbf, cols, wbf,
                                                                     bias, out);
    } else {
        bsl_fallback<<<dim3(rb * (batch / MT)), dim3(256), 0, stream>>>(
            x, crow, cols, weight, mask, bias, out);
    }
}